// Round 6
// baseline (555.921 us; speedup 1.0000x reference)
//
#include <hip/hip_runtime.h>
#include <math.h>

// Problem constants: B=32, M=16, S=64, Q=48, E=128, D=2E=256
constexpr int Bc = 32, Mc = 16, Sc = 64, Qc = 48, Dc = 256;
constexpr int UPAD1 = 260;  // K1 u row stride (floats): 1040 B, 16B-aligned, even bank spread

// async global->LDS, 16B per lane (wave-uniform LDS base, per-lane global addr)
__device__ __forceinline__ void gload_lds16(const float* g, float* l) {
    __builtin_amdgcn_global_load_lds(
        (const __attribute__((address_space(1))) void*)(g),
        (__attribute__((address_space(3))) void*)(l), 16, 0, 0);
}

// ---------------- Kernel 1: scores -> a (normalized), h_att ----------------
// one block per (b,m); 512 threads = 8 waves; wave owns 8 rows (i)
__global__ __launch_bounds__(512, 1)
void attn_scores(const float* __restrict__ h_g, const float* __restrict__ u_g,
                 const float* __restrict__ W, const float* __restrict__ b_g,
                 float* __restrict__ a_ws, float* __restrict__ hatt_ws)
{
    __shared__ __align__(16) float u_lds[Qc][UPAD1];  // 49,920 B (becomes u*w_hu in place)
    __shared__ __align__(16) float h_lds[Sc][Dc];     // 65,536 B
    __shared__ float su_lds[Qc];
    __shared__ float hw_lds[Sc];
    __shared__ float rowmax_lds[Sc];

    const int tid  = threadIdx.x;
    const int lane = tid & 63;
    const int wave = __builtin_amdgcn_readfirstlane(tid >> 6);
    const int bm   = blockIdx.x;
    const int b    = bm >> 4;

    // stage h (8 rows/wave) and u (6 rows/wave) straight into LDS
    {
        const float* hb = h_g + (size_t)bm * Sc * Dc + lane * 4;
#pragma unroll
        for (int r = 0; r < 8; ++r) {
            const int i = wave * 8 + r;
            gload_lds16(hb + i * Dc, &h_lds[i][0]);
        }
        const float* ub = u_g + (size_t)b * Qc * Dc + lane * 4;
#pragma unroll
        for (int t = 0; t < 6; ++t) {
            const int j = wave + 8 * t;
            gload_lds16(ub + j * Dc, &u_lds[j][0]);
        }
    }
    const float4 wh4  = ((const float4*)W)[lane];
    const float4 wu4  = ((const float4*)(W + Dc))[lane];
    const float4 whu4 = ((const float4*)(W + 2 * Dc))[lane];
    const float  bias = b_g[0];
    __syncthreads();

    // phase 2: su[j] = u_j.w_u, then overwrite u_lds[j] with u_j * w_hu; hw[i] = h_i.w_h
#pragma unroll
    for (int t = 0; t < 6; ++t) {
        const int j = wave + 8 * t;
        float4 uv = *(const float4*)&u_lds[j][4 * lane];
        float p = uv.x * wu4.x + uv.y * wu4.y + uv.z * wu4.z + uv.w * wu4.w;
        for (int o = 32; o > 0; o >>= 1) p += __shfl_xor(p, o);
        if (lane == 0) su_lds[j] = p;
        float4 up;
        up.x = uv.x * whu4.x; up.y = uv.y * whu4.y;
        up.z = uv.z * whu4.z; up.w = uv.w * whu4.w;
        *(float4*)&u_lds[j][4 * lane] = up;
    }
#pragma unroll
    for (int r = 0; r < 8; ++r) {
        const int i = wave * 8 + r;
        const float4 hv = *(const float4*)&h_lds[i][4 * lane];
        float p = hv.x * wh4.x + hv.y * wh4.y + hv.z * wh4.z + hv.w * wh4.w;
        for (int o = 32; o > 0; o >>= 1) p += __shfl_xor(p, o);
        if (lane == 0) hw_lds[i] = p;
    }
    __syncthreads();

    // phase 3: s rows; lane = j, wave owns rows i0..i0+7
    const int j  = (lane < Qc) ? lane : 0;
    const int i0 = wave * 8;
    float acc[8] = {0.f, 0.f, 0.f, 0.f, 0.f, 0.f, 0.f, 0.f};
    {
        const float4* urow = (const float4*)&u_lds[j][0];
#pragma unroll 4
        for (int d4 = 0; d4 < Dc / 4; ++d4) {
            const float4 uv = urow[d4];  // u_j * w_hu
#pragma unroll
            for (int r = 0; r < 8; ++r) {
                const float4 hv = ((const float4*)&h_lds[i0 + r][0])[d4];  // broadcast
                acc[r] += hv.x * uv.x + hv.y * uv.y + hv.z * uv.z + hv.w * uv.w;
            }
        }
    }
    const float suj = su_lds[j];
#pragma unroll
    for (int r = 0; r < 8; ++r) {
        const int i = i0 + r;
        const float s  = acc[r] + hw_lds[i] + suj + bias;
        const float sv = (lane < Qc) ? s : -INFINITY;
        float m = sv;
        for (int o = 32; o > 0; o >>= 1) m = fmaxf(m, __shfl_xor(m, o));
        float e = (lane < Qc) ? __expf(sv - m) : 0.f;
        float sum = e;
        for (int o = 32; o > 0; o >>= 1) sum += __shfl_xor(sum, o);
        const float rinv = 1.0f / sum;
        if (lane < Qc) a_ws[((size_t)bm * Sc + i) * Qc + lane] = e * rinv;
        if (lane == 0) rowmax_lds[i] = m;
    }
    __syncthreads();
    if (wave != 0) return;

    // phase B (wave 0): p = softmax_i(rowmax); h_att = sum_i p_i h_i
    const float pm = rowmax_lds[lane];
    float mm = pm;
    for (int o = 32; o > 0; o >>= 1) mm = fmaxf(mm, __shfl_xor(mm, o));
    const float pe = __expf(pm - mm);
    float ps = pe;
    for (int o = 32; o > 0; o >>= 1) ps += __shfl_xor(ps, o);
    const float pv = pe / ps;  // p_i for i = lane
    float4 hacc = {0.f, 0.f, 0.f, 0.f};
    for (int i = 0; i < Sc; ++i) {
        const float pi = __shfl(pv, i);
        const float4 hv = ((const float4*)&h_lds[i][0])[lane];
        hacc.x += pi * hv.x; hacc.y += pi * hv.y;
        hacc.z += pi * hv.z; hacc.w += pi * hv.w;
    }
    ((float4*)(hatt_ws + (size_t)bm * Dc))[lane] = hacc;
}

// ---------------- Kernel 2: streaming outputs ----------------
// one block per (b,m); LDS = u tile only (~49 KB) -> 3 blocks/CU
__global__ __launch_bounds__(512)
void attn_out(const float* __restrict__ h_g, const float* __restrict__ u_g,
              const float* __restrict__ a_ws, const float* __restrict__ hatt_ws,
              float* __restrict__ out)
{
    __shared__ __align__(16) float u_lds[Qc][Dc];  // 49,152 B

    const int tid  = threadIdx.x;
    const int lane = tid & 63;
    const int wave = __builtin_amdgcn_readfirstlane(tid >> 6);
    const int bm   = blockIdx.x;
    const int b    = bm >> 4;

    {
        const float* ub = u_g + (size_t)b * Qc * Dc + lane * 4;
#pragma unroll
        for (int t = 0; t < 6; ++t) {
            const int j = wave + 8 * t;
            gload_lds16(ub + j * Dc, &u_lds[j][0]);
        }
    }
    const float4 hatt = ((const float4*)(hatt_ws + (size_t)bm * Dc))[lane];
    __syncthreads();

    const float4* h4   = (const float4*)(h_g + (size_t)bm * Sc * Dc);
    float4*       out4 = (float4*)out;

    for (int pass = 0; pass < 4; ++pass) {
        const int i0 = wave * 8 + pass * 2;
        const int i1 = i0 + 1;
        const float4 hv0 = h4[i0 * 64 + lane];
        const float4 hv1 = h4[i1 * 64 + lane];
        const float* a0 = a_ws + ((size_t)bm * Sc + i0) * Qc;  // wave-uniform -> s_load
        const float* a1 = a0 + Qc;
        float4 A0 = {0.f, 0.f, 0.f, 0.f};
        float4 A1 = {0.f, 0.f, 0.f, 0.f};
#pragma unroll
        for (int jj = 0; jj < Qc; ++jj) {
            const float4 uv = *(const float4*)&u_lds[jj][4 * lane];
            const float c0 = a0[jj];
            const float c1 = a1[jj];
            A0.x += c0 * uv.x; A0.y += c0 * uv.y; A0.z += c0 * uv.z; A0.w += c0 * uv.w;
            A1.x += c1 * uv.x; A1.y += c1 * uv.y; A1.z += c1 * uv.z; A1.w += c1 * uv.w;
        }
        float4 hu0, hu1, hh0, hh1;
        hu0.x = hv0.x * A0.x; hu0.y = hv0.y * A0.y; hu0.z = hv0.z * A0.z; hu0.w = hv0.w * A0.w;
        hu1.x = hv1.x * A1.x; hu1.y = hv1.y * A1.y; hu1.z = hv1.z * A1.z; hu1.w = hv1.w * A1.w;
        hh0.x = hv0.x * hatt.x; hh0.y = hv0.y * hatt.y; hh0.z = hv0.z * hatt.z; hh0.w = hv0.w * hatt.w;
        hh1.x = hv1.x * hatt.x; hh1.y = hv1.y * hatt.y; hh1.z = hv1.z * hatt.z; hh1.w = hv1.w * hatt.w;

        const size_t base0 = ((size_t)bm * Sc + i0) * 256;  // float4 units per row = 256
        const size_t base1 = base0 + 256;
        out4[base0 +       lane] = hv0;
        out4[base0 +  64 + lane] = A0;
        out4[base0 + 128 + lane] = hu0;
        out4[base0 + 192 + lane] = hh0;
        out4[base1 +       lane] = hv1;
        out4[base1 +  64 + lane] = A1;
        out4[base1 + 128 + lane] = hu1;
        out4[base1 + 192 + lane] = hh1;
    }
}

extern "C" void kernel_launch(void* const* d_in, const int* in_sizes, int n_in,
                              void* d_out, int out_size, void* d_ws, size_t ws_size,
                              hipStream_t stream) {
    const float* h = (const float*)d_in[0];   // (B,M,S,D) f32
    const float* u = (const float*)d_in[1];   // (B,Q,D) f32
    const float* W = (const float*)d_in[2];   // (3D,) f32
    const float* b = (const float*)d_in[3];   // (1,) f32
    float* out = (float*)d_out;               // (B,M,S,4D) f32

    float* a_ws    = (float*)d_ws;                          // 512*64*48 f32 = 6.29 MB
    float* hatt_ws = a_ws + (size_t)Bc * Mc * Sc * Qc;      // 512*256 f32 = 0.52 MB

    attn_scores<<<dim3(Bc * Mc), dim3(512), 0, stream>>>(h, u, W, b, a_ws, hatt_ws);
    attn_out   <<<dim3(Bc * Mc), dim3(512), 0, stream>>>(h, u, a_ws, hatt_ws, out);
}

// Round 12
// 236.063 us; speedup vs baseline: 2.3550x; 2.3550x over previous
//
#include <hip/hip_runtime.h>
#include <math.h>

// Problem constants: B=32, M=16, S=64, Q=48, E=128, D=2E=256
constexpr int Bc = 32, Mc = 16, Sc = 64, Qc = 48, Dc = 256;
constexpr int UPAD = 260;  // u row stride (floats): 1040 B; banks (4j+4d4+w)%32 -> ~6-way on row reads

// async global->LDS, 16B/lane (wave-uniform LDS base, per-lane global addr)
__device__ __forceinline__ void gload_lds16(const float* g, float* l) {
    __builtin_amdgcn_global_load_lds(
        (const __attribute__((address_space(1))) void*)(g),
        (__attribute__((address_space(3))) void*)(l), 16, 0, 0);
}

typedef float f4v __attribute__((ext_vector_type(4)));
__device__ __forceinline__ void nt_store4(float* p, float4 v) {
    f4v t; t[0] = v.x; t[1] = v.y; t[2] = v.z; t[3] = v.w;
    __builtin_nontemporal_store(t, (f4v*)p);   // global_store_dwordx4 ... nt
}

// ---------------- K0: per-b prep: uhat = u * w_hu ; su[b][j] = u_j . w_u ----------------
__global__ __launch_bounds__(512)
void prep(const float* __restrict__ u_g, const float* __restrict__ W,
          float* __restrict__ uhat_ws, float* __restrict__ su_ws)
{
    const int tid  = threadIdx.x;
    const int lane = tid & 63;
    const int wave = tid >> 6;
    const int b    = blockIdx.x;
    const float4* u4  = (const float4*)(u_g + (size_t)b * Qc * Dc);
    float4*       uh4 = (float4*)(uhat_ws + (size_t)b * Qc * Dc);
    const float4* whu = (const float4*)(W + 2 * Dc);
#pragma unroll
    for (int k = 0; k < 6; ++k) {
        const int idx = tid + k * 512;       // 0..3071 float4s
        const int c   = idx & 63;
        const float4 uv = u4[idx];
        const float4 wv = whu[c];
        float4 r; r.x = uv.x * wv.x; r.y = uv.y * wv.y; r.z = uv.z * wv.z; r.w = uv.w * wv.w;
        uh4[idx] = r;
    }
    const float4 wu4 = ((const float4*)(W + Dc))[lane];
#pragma unroll
    for (int t = 0; t < 6; ++t) {
        const int j = wave + 8 * t;
        const float4 uv = u4[j * 64 + lane];
        float p = uv.x * wu4.x + uv.y * wu4.y + uv.z * wu4.z + uv.w * wu4.w;
        for (int o = 32; o > 0; o >>= 1) p += __shfl_xor(p, o);
        if (lane == 0) su_ws[b * Qc + j] = p;
    }
}

// ---------------- K1: scores -> a (normalized), rowmax ----------------
// grid 2048: blk = bm*4 + q; each block does 16 i-rows. LDS 66,304 B -> 2 blocks/CU.
__global__ __launch_bounds__(512, 4)
void attn_scores(const float* __restrict__ h_g, const float* __restrict__ uhat_ws,
                 const float* __restrict__ su_ws, const float* __restrict__ W,
                 float* __restrict__ a_ws, float* __restrict__ rowmax_ws)
{
    __shared__ __align__(16) float u_lds[Qc][UPAD];   // 49,920 B (uhat rows)
    __shared__ __align__(16) float h_lds[16][Dc];     // 16,384 B

    const int tid  = threadIdx.x;
    const int lane = tid & 63;
    const int wave = __builtin_amdgcn_readfirstlane(tid >> 6);
    const int blk  = blockIdx.x;
    const int bm   = blk >> 2;
    const int q    = blk & 3;
    const int b    = bm >> 4;
    const int ibase = q * 16;

    // stage: 2 h rows + 6 uhat rows per wave
    const int lr0 = wave * 2, lr1 = lr0 + 1;
    {
        const float* hb = h_g + ((size_t)bm * Sc + ibase) * Dc + lane * 4;
        gload_lds16(hb + lr0 * Dc, &h_lds[lr0][0]);
        gload_lds16(hb + lr1 * Dc, &h_lds[lr1][0]);
        const float* ub = uhat_ws + (size_t)b * Qc * Dc + lane * 4;
#pragma unroll
        for (int t = 0; t < 6; ++t) {
            const int j = wave + 8 * t;
            gload_lds16(ub + j * Dc, &u_lds[j][0]);
        }
    }
    const float4 wh4 = ((const float4*)W)[lane];
    const int   j   = (lane < Qc) ? lane : 0;
    const float suj = su_ws[b * Qc + j];
    __syncthreads();

    // hw for this wave's two rows (butterfly leaves value in all lanes)
    float hw0, hw1;
    {
        const float4 h0 = *(const float4*)&h_lds[lr0][4 * lane];
        float p = h0.x * wh4.x + h0.y * wh4.y + h0.z * wh4.z + h0.w * wh4.w;
        for (int o = 32; o > 0; o >>= 1) p += __shfl_xor(p, o);
        hw0 = p;
        const float4 h1 = *(const float4*)&h_lds[lr1][4 * lane];
        p = h1.x * wh4.x + h1.y * wh4.y + h1.z * wh4.z + h1.w * wh4.w;
        for (int o = 32; o > 0; o >>= 1) p += __shfl_xor(p, o);
        hw1 = p;
    }

    // s-dot: lane = j; two rows per wave
    float acc0 = 0.f, acc1 = 0.f;
    {
        const float4* urow = (const float4*)&u_lds[j][0];
#pragma unroll 4
        for (int d4 = 0; d4 < Dc / 4; ++d4) {
            const float4 uv = urow[d4];                              // ~6-way banked
            const float4 h0 = ((const float4*)&h_lds[lr0][0])[d4];   // broadcast
            const float4 h1 = ((const float4*)&h_lds[lr1][0])[d4];   // broadcast
            acc0 += h0.x * uv.x + h0.y * uv.y + h0.z * uv.z + h0.w * uv.w;
            acc1 += h1.x * uv.x + h1.y * uv.y + h1.z * uv.z + h1.w * uv.w;
        }
    }

    // row softmax over j (bias cancels; hw uniform per row -> only in rowmax)
#pragma unroll
    for (int r = 0; r < 2; ++r) {
        const float accr = r ? acc1 : acc0;
        const float hwr  = r ? hw1  : hw0;
        const int   i    = ibase + lr0 + r;
        const float sv   = (lane < Qc) ? (accr + suj) : -INFINITY;
        float m = sv;
        for (int o = 32; o > 0; o >>= 1) m = fmaxf(m, __shfl_xor(m, o));
        const float e = (lane < Qc) ? __expf(sv - m) : 0.f;
        float sum = e;
        for (int o = 32; o > 0; o >>= 1) sum += __shfl_xor(sum, o);
        const float rinv = 1.0f / sum;
        if (lane < Qc) a_ws[((size_t)bm * Sc + i) * Qc + lane] = e * rinv;
        if (lane == 0) rowmax_ws[(size_t)bm * Sc + i] = m + hwr;
    }
}

// ---------------- K2: streaming outputs (NT stores), h_att fused ----------------
// one block per bm; LDS u 48K + partials 8K; h rows live in registers.
__global__ __launch_bounds__(512)
void attn_out(const float* __restrict__ h_g, const float* __restrict__ u_g,
              const float* __restrict__ a_ws, const float* __restrict__ rowmax_ws,
              float* __restrict__ out)
{
    __shared__ __align__(16) float u_lds[Qc][Dc];   // 49,152 B
    __shared__ __align__(16) float part[8][Dc];     //  8,192 B

    const int tid  = threadIdx.x;
    const int lane = tid & 63;
    const int wave = __builtin_amdgcn_readfirstlane(tid >> 6);
    const int bm   = blockIdx.x;
    const int b    = bm >> 4;

    {
        const float* ub = u_g + (size_t)b * Qc * Dc + lane * 4;
#pragma unroll
        for (int t = 0; t < 6; ++t) {
            const int j = wave + 8 * t;
            gload_lds16(ub + j * Dc, &u_lds[j][0]);
        }
    }

    // this wave's 8 h rows -> registers (read once from HBM/L3)
    const float4* h4 = (const float4*)(h_g + (size_t)bm * Sc * Dc);
    float4 hreg[8];
#pragma unroll
    for (int r = 0; r < 8; ++r) hreg[r] = h4[(wave * 8 + r) * 64 + lane];

    // p = softmax_i(rowmax) (redundant per wave; i = lane)
    const float pm = rowmax_ws[(size_t)bm * Sc + lane];
    float mm = pm;
    for (int o = 32; o > 0; o >>= 1) mm = fmaxf(mm, __shfl_xor(mm, o));
    const float pe = __expf(pm - mm);
    float ps = pe;
    for (int o = 32; o > 0; o >>= 1) ps += __shfl_xor(ps, o);
    const float pv = pe / ps;

    // h_att: per-wave partial over its 8 rows, then cross-wave LDS reduce
    float4 hp = {0.f, 0.f, 0.f, 0.f};
#pragma unroll
    for (int r = 0; r < 8; ++r) {
        const float pi = __shfl(pv, wave * 8 + r);
        hp.x += pi * hreg[r].x; hp.y += pi * hreg[r].y;
        hp.z += pi * hreg[r].z; hp.w += pi * hreg[r].w;
    }
    *(float4*)&part[wave][4 * lane] = hp;
    __syncthreads();
    float4 hatt = {0.f, 0.f, 0.f, 0.f};
#pragma unroll
    for (int w = 0; w < 8; ++w) {
        const float4 t = *(const float4*)&part[w][4 * lane];
        hatt.x += t.x; hatt.y += t.y; hatt.z += t.z; hatt.w += t.w;
    }

    // outputs: 2 passes x 4 rows; u_att from LDS u + wave-uniform a scalars
    for (int pass = 0; pass < 2; ++pass) {
        const float* ap = a_ws + ((size_t)bm * Sc + wave * 8 + pass * 4) * Qc;
        float4 A0 = {0.f,0.f,0.f,0.f}, A1 = {0.f,0.f,0.f,0.f};
        float4 A2 = {0.f,0.f,0.f,0.f}, A3 = {0.f,0.f,0.f,0.f};
#pragma unroll
        for (int jj = 0; jj < Qc; ++jj) {
            const float4 uv = *(const float4*)&u_lds[jj][4 * lane];  // conflict-free
            const float c0 = ap[jj], c1 = ap[Qc + jj], c2 = ap[2 * Qc + jj], c3 = ap[3 * Qc + jj];
            A0.x += c0 * uv.x; A0.y += c0 * uv.y; A0.z += c0 * uv.z; A0.w += c0 * uv.w;
            A1.x += c1 * uv.x; A1.y += c1 * uv.y; A1.z += c1 * uv.z; A1.w += c1 * uv.w;
            A2.x += c2 * uv.x; A2.y += c2 * uv.y; A2.z += c2 * uv.z; A2.w += c2 * uv.w;
            A3.x += c3 * uv.x; A3.y += c3 * uv.y; A3.z += c3 * uv.z; A3.w += c3 * uv.w;
        }
#pragma unroll
        for (int k = 0; k < 4; ++k) {
            const int r = pass * 4 + k;
            const float4 hv = hreg[r];
            const float4 ua = (k == 0) ? A0 : (k == 1) ? A1 : (k == 2) ? A2 : A3;
            float4 hu, hh;
            hu.x = hv.x * ua.x; hu.y = hv.y * ua.y; hu.z = hv.z * ua.z; hu.w = hv.w * ua.w;
            hh.x = hv.x * hatt.x; hh.y = hv.y * hatt.y; hh.z = hv.z * hatt.z; hh.w = hv.w * hatt.w;
            float* rowp = out + (((size_t)bm * Sc + wave * 8 + r) * 4 * Dc);
            nt_store4(rowp +           lane * 4, hv);
            nt_store4(rowp + Dc     + lane * 4, ua);
            nt_store4(rowp + 2 * Dc + lane * 4, hu);
            nt_store4(rowp + 3 * Dc + lane * 4, hh);
        }
    }
}

extern "C" void kernel_launch(void* const* d_in, const int* in_sizes, int n_in,
                              void* d_out, int out_size, void* d_ws, size_t ws_size,
                              hipStream_t stream) {
    const float* h = (const float*)d_in[0];   // (B,M,S,D) f32
    const float* u = (const float*)d_in[1];   // (B,Q,D) f32
    const float* W = (const float*)d_in[2];   // (3D,) f32
    // d_in[3] = b (bias cancels in both softmaxes -> unused)
    float* out = (float*)d_out;               // (B,M,S,4D) f32

    float* a_ws      = (float*)d_ws;                              // 6.29 MB
    float* rowmax_ws = a_ws + (size_t)Bc * Mc * Sc * Qc;          // 0.13 MB
    float* uhat_ws   = rowmax_ws + (size_t)Bc * Mc * Sc;          // 1.57 MB
    float* su_ws     = uhat_ws + (size_t)Bc * Qc * Dc;            // 6 KB   (total ~8.0 MB)

    prep       <<<dim3(Bc),          dim3(512), 0, stream>>>(u, W, uhat_ws, su_ws);
    attn_scores<<<dim3(Bc * Mc * 4), dim3(512), 0, stream>>>(h, uhat_ws, su_ws, W, a_ws, rowmax_ws);
    attn_out   <<<dim3(Bc * Mc),     dim3(512), 0, stream>>>(h, u, a_ws, rowmax_ws, out);
}

// Round 13
// 235.025 us; speedup vs baseline: 2.3654x; 1.0044x over previous
//
#include <hip/hip_runtime.h>
#include <math.h>

// Problem constants: B=32, M=16, S=64, Q=48, E=128, D=2E=256
constexpr int Bc = 32, Mc = 16, Sc = 64, Qc = 48, Dc = 256;
constexpr int UPAD = 260;  // padded row stride (floats): 1040 B, 16B-aligned.
                           // Breaks the stride-256 bank pattern on b128 row reads:
                           // measured 266K conflicts (round 1, padded) vs 1.57M (round 12, unpadded).

// async global->LDS, 16B/lane (wave-uniform LDS base, per-lane global addr)
__device__ __forceinline__ void gload_lds16(const float* g, float* l) {
    __builtin_amdgcn_global_load_lds(
        (const __attribute__((address_space(1))) void*)(g),
        (__attribute__((address_space(3))) void*)(l), 16, 0, 0);
}

typedef float f4v __attribute__((ext_vector_type(4)));
__device__ __forceinline__ void nt_store4(float* p, float4 v) {
    f4v t; t[0] = v.x; t[1] = v.y; t[2] = v.z; t[3] = v.w;
    __builtin_nontemporal_store(t, (f4v*)p);   // global_store_dwordx4 ... nt
}

// ---------------- K0: per-b prep: uhat = u * w_hu ; su[b][j] = u_j . w_u ----------------
__global__ __launch_bounds__(512)
void prep(const float* __restrict__ u_g, const float* __restrict__ W,
          float* __restrict__ uhat_ws, float* __restrict__ su_ws)
{
    const int tid  = threadIdx.x;
    const int lane = tid & 63;
    const int wave = tid >> 6;
    const int b    = blockIdx.x;
    const float4* u4  = (const float4*)(u_g + (size_t)b * Qc * Dc);
    float4*       uh4 = (float4*)(uhat_ws + (size_t)b * Qc * Dc);
    const float4* whu = (const float4*)(W + 2 * Dc);
#pragma unroll
    for (int k = 0; k < 6; ++k) {
        const int idx = tid + k * 512;       // 0..3071 float4s
        const int c   = idx & 63;
        const float4 uv = u4[idx];
        const float4 wv = whu[c];
        float4 r; r.x = uv.x * wv.x; r.y = uv.y * wv.y; r.z = uv.z * wv.z; r.w = uv.w * wv.w;
        uh4[idx] = r;
    }
    const float4 wu4 = ((const float4*)(W + Dc))[lane];
#pragma unroll
    for (int t = 0; t < 6; ++t) {
        const int j = wave + 8 * t;
        const float4 uv = u4[j * 64 + lane];
        float p = uv.x * wu4.x + uv.y * wu4.y + uv.z * wu4.z + uv.w * wu4.w;
        for (int o = 32; o > 0; o >>= 1) p += __shfl_xor(p, o);
        if (lane == 0) su_ws[b * Qc + j] = p;
    }
}

// ---------------- K1: scores -> a (normalized), rowmax ----------------
// grid 2048: blk = bm*4 + q; each block does 16 i-rows. LDS 66,304 B -> 2 blocks/CU.
__global__ __launch_bounds__(512, 4)
void attn_scores(const float* __restrict__ h_g, const float* __restrict__ uhat_ws,
                 const float* __restrict__ su_ws, const float* __restrict__ W,
                 float* __restrict__ a_ws, float* __restrict__ rowmax_ws)
{
    __shared__ __align__(16) float u_lds[Qc][UPAD];   // 49,920 B (uhat rows)
    __shared__ __align__(16) float h_lds[16][Dc];     // 16,384 B

    const int tid  = threadIdx.x;
    const int lane = tid & 63;
    const int wave = __builtin_amdgcn_readfirstlane(tid >> 6);
    const int blk  = blockIdx.x;
    const int bm   = blk >> 2;
    const int q    = blk & 3;
    const int b    = bm >> 4;
    const int ibase = q * 16;

    // stage: 2 h rows + 6 uhat rows per wave
    const int lr0 = wave * 2, lr1 = lr0 + 1;
    {
        const float* hb = h_g + ((size_t)bm * Sc + ibase) * Dc + lane * 4;
        gload_lds16(hb + lr0 * Dc, &h_lds[lr0][0]);
        gload_lds16(hb + lr1 * Dc, &h_lds[lr1][0]);
        const float* ub = uhat_ws + (size_t)b * Qc * Dc + lane * 4;
#pragma unroll
        for (int t = 0; t < 6; ++t) {
            const int j = wave + 8 * t;
            gload_lds16(ub + j * Dc, &u_lds[j][0]);
        }
    }
    const float4 wh4 = ((const float4*)W)[lane];
    const int   j   = (lane < Qc) ? lane : 0;
    const float suj = su_ws[b * Qc + j];
    __syncthreads();

    // hw for this wave's two rows (butterfly leaves value in all lanes)
    float hw0, hw1;
    {
        const float4 h0 = *(const float4*)&h_lds[lr0][4 * lane];
        float p = h0.x * wh4.x + h0.y * wh4.y + h0.z * wh4.z + h0.w * wh4.w;
        for (int o = 32; o > 0; o >>= 1) p += __shfl_xor(p, o);
        hw0 = p;
        const float4 h1 = *(const float4*)&h_lds[lr1][4 * lane];
        p = h1.x * wh4.x + h1.y * wh4.y + h1.z * wh4.z + h1.w * wh4.w;
        for (int o = 32; o > 0; o >>= 1) p += __shfl_xor(p, o);
        hw1 = p;
    }

    // s-dot: lane = j; two rows per wave
    float acc0 = 0.f, acc1 = 0.f;
    {
        const float4* urow = (const float4*)&u_lds[j][0];
#pragma unroll 4
        for (int d4 = 0; d4 < Dc / 4; ++d4) {
            const float4 uv = urow[d4];                              // ~6-way banked (padded)
            const float4 h0 = ((const float4*)&h_lds[lr0][0])[d4];   // broadcast
            const float4 h1 = ((const float4*)&h_lds[lr1][0])[d4];   // broadcast
            acc0 += h0.x * uv.x + h0.y * uv.y + h0.z * uv.z + h0.w * uv.w;
            acc1 += h1.x * uv.x + h1.y * uv.y + h1.z * uv.z + h1.w * uv.w;
        }
    }

    // row softmax over j (bias cancels; hw uniform per row -> only in rowmax)
#pragma unroll
    for (int r = 0; r < 2; ++r) {
        const float accr = r ? acc1 : acc0;
        const float hwr  = r ? hw1  : hw0;
        const int   i    = ibase + lr0 + r;
        const float sv   = (lane < Qc) ? (accr + suj) : -INFINITY;
        float m = sv;
        for (int o = 32; o > 0; o >>= 1) m = fmaxf(m, __shfl_xor(m, o));
        const float e = (lane < Qc) ? __expf(sv - m) : 0.f;
        float sum = e;
        for (int o = 32; o > 0; o >>= 1) sum += __shfl_xor(sum, o);
        const float rinv = 1.0f / sum;
        if (lane < Qc) a_ws[((size_t)bm * Sc + i) * Qc + lane] = e * rinv;
        if (lane == 0) rowmax_ws[(size_t)bm * Sc + i] = m + hwr;
    }
}

// ---------------- K2: streaming outputs (NT stores), h_att fused ----------------
// one block per bm; LDS: padded u tile + padded partials; h rows in registers.
__global__ __launch_bounds__(512)
void attn_out(const float* __restrict__ h_g, const float* __restrict__ u_g,
              const float* __restrict__ a_ws, const float* __restrict__ rowmax_ws,
              float* __restrict__ out)
{
    __shared__ __align__(16) float u_lds[Qc][UPAD];   // 49,920 B  (stride 260: kills stride-256 conflicts)
    __shared__ __align__(16) float part[8][UPAD];     //  8,320 B

    const int tid  = threadIdx.x;
    const int lane = tid & 63;
    const int wave = __builtin_amdgcn_readfirstlane(tid >> 6);
    const int bm   = blockIdx.x;
    const int b    = bm >> 4;

    {
        const float* ub = u_g + (size_t)b * Qc * Dc + lane * 4;
#pragma unroll
        for (int t = 0; t < 6; ++t) {
            const int j = wave + 8 * t;
            gload_lds16(ub + j * Dc, &u_lds[j][0]);   // lanes fill first 1024B of 1040B row
        }
    }

    // this wave's 8 h rows -> registers (read once from HBM/L3)
    const float4* h4 = (const float4*)(h_g + (size_t)bm * Sc * Dc);
    float4 hreg[8];
#pragma unroll
    for (int r = 0; r < 8; ++r) hreg[r] = h4[(wave * 8 + r) * 64 + lane];

    // p = softmax_i(rowmax) (redundant per wave; i = lane)
    const float pm = rowmax_ws[(size_t)bm * Sc + lane];
    float mm = pm;
    for (int o = 32; o > 0; o >>= 1) mm = fmaxf(mm, __shfl_xor(mm, o));
    const float pe = __expf(pm - mm);
    float ps = pe;
    for (int o = 32; o > 0; o >>= 1) ps += __shfl_xor(ps, o);
    const float pv = pe / ps;

    // h_att: per-wave partial over its 8 rows, then cross-wave LDS reduce
    float4 hp = {0.f, 0.f, 0.f, 0.f};
#pragma unroll
    for (int r = 0; r < 8; ++r) {
        const float pi = __shfl(pv, wave * 8 + r);
        hp.x += pi * hreg[r].x; hp.y += pi * hreg[r].y;
        hp.z += pi * hreg[r].z; hp.w += pi * hreg[r].w;
    }
    *(float4*)&part[wave][4 * lane] = hp;
    __syncthreads();
    float4 hatt = {0.f, 0.f, 0.f, 0.f};
#pragma unroll
    for (int w = 0; w < 8; ++w) {
        const float4 t = *(const float4*)&part[w][4 * lane];
        hatt.x += t.x; hatt.y += t.y; hatt.z += t.z; hatt.w += t.w;
    }

    // outputs: 2 passes x 4 rows; u_att from LDS u + wave-uniform a scalars
    for (int pass = 0; pass < 2; ++pass) {
        const float* ap = a_ws + ((size_t)bm * Sc + wave * 8 + pass * 4) * Qc;
        float4 A0 = {0.f,0.f,0.f,0.f}, A1 = {0.f,0.f,0.f,0.f};
        float4 A2 = {0.f,0.f,0.f,0.f}, A3 = {0.f,0.f,0.f,0.f};
#pragma unroll
        for (int jj = 0; jj < Qc; ++jj) {
            const float4 uv = *(const float4*)&u_lds[jj][4 * lane];  // padded stride
            const float c0 = ap[jj], c1 = ap[Qc + jj], c2 = ap[2 * Qc + jj], c3 = ap[3 * Qc + jj];
            A0.x += c0 * uv.x; A0.y += c0 * uv.y; A0.z += c0 * uv.z; A0.w += c0 * uv.w;
            A1.x += c1 * uv.x; A1.y += c1 * uv.y; A1.z += c1 * uv.z; A1.w += c1 * uv.w;
            A2.x += c2 * uv.x; A2.y += c2 * uv.y; A2.z += c2 * uv.z; A2.w += c2 * uv.w;
            A3.x += c3 * uv.x; A3.y += c3 * uv.y; A3.z += c3 * uv.z; A3.w += c3 * uv.w;
        }
#pragma unroll
        for (int k = 0; k < 4; ++k) {
            const int r = pass * 4 + k;
            const float4 hv = hreg[r];
            const float4 ua = (k == 0) ? A0 : (k == 1) ? A1 : (k == 2) ? A2 : A3;
            float4 hu, hh;
            hu.x = hv.x * ua.x; hu.y = hv.y * ua.y; hu.z = hv.z * ua.z; hu.w = hv.w * ua.w;
            hh.x = hv.x * hatt.x; hh.y = hv.y * hatt.y; hh.z = hv.z * hatt.z; hh.w = hv.w * hatt.w;
            float* rowp = out + (((size_t)bm * Sc + wave * 8 + r) * 4 * Dc);
            nt_store4(rowp +           lane * 4, hv);
            nt_store4(rowp + Dc     + lane * 4, ua);
            nt_store4(rowp + 2 * Dc + lane * 4, hu);
            nt_store4(rowp + 3 * Dc + lane * 4, hh);
        }
    }
}

extern "C" void kernel_launch(void* const* d_in, const int* in_sizes, int n_in,
                              void* d_out, int out_size, void* d_ws, size_t ws_size,
                              hipStream_t stream) {
    const float* h = (const float*)d_in[0];   // (B,M,S,D) f32
    const float* u = (const float*)d_in[1];   // (B,Q,D) f32
    const float* W = (const float*)d_in[2];   // (3D,) f32
    // d_in[3] = b (bias cancels in both softmaxes -> unused)
    float* out = (float*)d_out;               // (B,M,S,4D) f32

    float* a_ws      = (float*)d_ws;                              // 6.29 MB
    float* rowmax_ws = a_ws + (size_t)Bc * Mc * Sc * Qc;          // 0.13 MB
    float* uhat_ws   = rowmax_ws + (size_t)Bc * Mc * Sc;          // 1.57 MB
    float* su_ws     = uhat_ws + (size_t)Bc * Qc * Dc;            // 6 KB   (total ~8.0 MB)

    prep       <<<dim3(Bc),          dim3(512), 0, stream>>>(u, W, uhat_ws, su_ws);
    attn_scores<<<dim3(Bc * Mc * 4), dim3(512), 0, stream>>>(h, uhat_ws, su_ws, W, a_ws, rowmax_ws);
    attn_out   <<<dim3(Bc * Mc),     dim3(512), 0, stream>>>(h, u, a_ws, rowmax_ws, out);
}